// Round 20
// baseline (122.978 us; speedup 1.0000x reference)
//
#include <hip/hip_runtime.h>

typedef float f32x4 __attribute__((ext_vector_type(4)));

// x: [1, 2049, 8192] f32 ; lambda: [1, 8192] f32
// out: [1, 1+2048+8192, 8192] f32
//
// R20: R16's split K1, with K0 given enough TLP. Mechanism: a pure-read
// kernel at 256 blocks holds only ~4MB in flight < 5.7MB needed for 6.3TB/s
// at ~900ns HBM latency (Little's law) -> R16's K0 was latency-starved.
// 1024 blocks (PBY=128) fixes that. Plain loads warm L3 (x=67MB fits 256MB)
// so K1b's linear copy re-reads x warm.

// K0: pure-read abs-sum reducer. grid (8, 128), block 256, plain loads.
__global__ __launch_bounds__(256) void k_abs_reduce(
    const float* __restrict__ x, float* __restrict__ partials,
    int N, int rowsPerChunk)
{
    const int col = (blockIdx.x * 256 + threadIdx.x) * 4;
    const int r0  = 1 + blockIdx.y * rowsPerChunk;
    f32x4 acc = {0.f, 0.f, 0.f, 0.f};
    #pragma unroll 4
    for (int r = r0; r < r0 + rowsPerChunk; ++r) {
        const f32x4 v = *(const f32x4*)(x + (size_t)r * N + col);  // plain: warms L3
        acc.x += fabsf(v.x); acc.y += fabsf(v.y); acc.z += fabsf(v.z); acc.w += fabsf(v.w);
    }
    *(f32x4*)(partials + (size_t)blockIdx.y * N + col) = acc;
}

// K1b: errs rows as pure linear grid-stride scaled copy (m13 pattern,
// plain/plain); reads x L3-warm after K0.
__global__ __launch_bounds__(256) void k_scale_copy(
    const float* __restrict__ x, const float* __restrict__ lam,
    float* __restrict__ out, long i0, long i1, int lamMask)
{
    const f32x4* xv = (const f32x4*)x;
    const f32x4* lv = (const f32x4*)lam;
    f32x4*       ov = (f32x4*)out;
    const long stride = (long)gridDim.x * 256;
    for (long i = i0 + (long)blockIdx.x * 256 + threadIdx.x; i < i1; i += stride)
        ov[i] = xv[i] * lv[i & lamMask];
}

// K2: reduce partials per column, write center (out row 0), flags, vals.
__global__ __launch_bounds__(256) void k_stats(
    const float* __restrict__ x, const float* __restrict__ lam,
    const float* __restrict__ partials,
    float* __restrict__ out, float* __restrict__ vals, int* __restrict__ flags,
    int N, int P)
{
    const int n = blockIdx.x * 256 + threadIdx.x;
    float s = 0.f;
    for (int p = 0; p < P; ++p) s += partials[(size_t)p * N + n];
    const float x0 = x[n];          // row 0 of x
    const float l  = lam[n];
    const float lower = x0 - s;
    const float upper = x0 + s;
    out[n] = l * x0 - l * lower * 0.5f;          // center
    const bool has = (lower < 0.f) && (upper > 0.f);
    flags[n] = has ? 1 : 0;
    vals[n]  = has ? (-l * lower * 0.5f) : 0.f;
}

// K3: single-block scan of flags -> inverse map colOfRow[r] = column (or -1).
__global__ __launch_bounds__(256) void k_scan(
    const int* __restrict__ flags, int* __restrict__ colOfRow, int N)
{
    __shared__ int waveSums[4];
    const int t    = threadIdx.x;
    const int per  = N / 256;         // 32
    const int base = t * per;
    int f[32];
    int cnt = 0;
    #pragma unroll
    for (int i = 0; i < 32; ++i) {
        f[i] = flags[base + i];
        cnt += f[i];
        colOfRow[base + i] = -1;      // init; ordered vs scatter by barrier below
    }
    const int lane = t & 63;
    const int wid  = t >> 6;
    int v = cnt;
    #pragma unroll
    for (int off = 1; off < 64; off <<= 1) {
        const int u = __shfl_up(v, off, 64);
        if (lane >= off) v += u;
    }
    if (lane == 63) waveSums[wid] = v;
    __syncthreads();
    int wadd = 0;
    for (int w = 0; w < wid; ++w) wadd += waveSums[w];
    int run = v - cnt + wadd;         // exclusive prefix
    #pragma unroll
    for (int i = 0; i < 32; ++i) {
        if (f[i]) { colOfRow[run] = base + i; run += 1; }
    }
}

// K4: extra block, row-owned: block b fills rpb=8 contiguous rows (256 KB
// linear) injecting vals[colOfRow[r]]. Plain stores.
__global__ __launch_bounds__(256) void k_extra_rows(
    const float* __restrict__ vals, const int* __restrict__ colOfRow,
    float* __restrict__ outExtra, int N, int rowsPerBlock)
{
    const int t  = threadIdx.x;
    const int r0 = blockIdx.x * rowsPerBlock;
    for (int r = r0; r < r0 + rowsPerBlock; ++r) {
        const int   c  = colOfRow[r];             // broadcast scalar read
        const float vv = (c >= 0) ? vals[c] : 0.f;
        float* rowp = outExtra + (size_t)r * N;
        #pragma unroll
        for (int s = 0; s < 8; ++s) {
            const int col = (s * 256 + t) * 4;
            f32x4 o;
            o.x = (c == col    ) ? vv : 0.f;
            o.y = (c == col + 1) ? vv : 0.f;
            o.z = (c == col + 2) ? vv : 0.f;
            o.w = (c == col + 3) ? vv : 0.f;
            *(f32x4*)(rowp + col) = o;            // plain store
        }
    }
}

extern "C" void kernel_launch(void* const* d_in, const int* in_sizes, int n_in,
                              void* d_out, int out_size, void* d_ws, size_t ws_size,
                              hipStream_t stream) {
    const float* x   = (const float*)d_in[0];
    const float* lam = (const float*)d_in[1];
    float* out = (float*)d_out;

    const int N  = in_sizes[1];            // 8192
    const int E1 = in_sizes[0] / N;        // 2049
    const int E  = E1 - 1;                 // 2048

    float* outExtra = out + (size_t)E1 * N;
    dim3 blk(256);

    // K0 TLP: prefer PBY=128 (1024 blocks, 4 MB partials); fall back if ws small.
    int PBY = 32;
    for (int cand : {128, 64, 32}) {
        const size_t need = ((size_t)cand * N + 3 * (size_t)N) * 4;
        if ((E % cand) == 0 && need <= ws_size) { PBY = cand; break; }
    }

    float* partials = (float*)d_ws;                     // [PBY][N]
    float* vals     = partials + (size_t)PBY * N;       // [N]
    int*   flags    = (int*)(vals + N);                 // [N]
    int*   colOfRow = flags + N;                        // [N]

    // K0: pure-read abs-sum at high TLP (plain loads warm L3 for K1b)
    hipLaunchKernelGGL(k_abs_reduce, dim3(N / 1024, PBY), blk, 0, stream,
                       x, partials, N, E / PBY);

    // K1b: pure linear scaled copy of rows 1..E (f32x4 flat range)
    const long i0 = (long)N / 4;                 // row 1
    const long i1 = (long)E1 * N / 4;            // end of row E
    hipLaunchKernelGGL(k_scale_copy, dim3(2048), blk, 0, stream,
                       x, lam, out, i0, i1, N / 4 - 1);

    hipLaunchKernelGGL(k_stats, dim3(N / 256), blk, 0, stream,
                       x, lam, partials, out, vals, flags, N, PBY);

    hipLaunchKernelGGL(k_scan, dim3(1), blk, 0, stream,
                       flags, colOfRow, N);

    const int rpb = 8;                     // 1024 blocks, 256 KB linear per block
    hipLaunchKernelGGL(k_extra_rows, dim3(N / rpb), blk, 0, stream,
                       vals, colOfRow, outExtra, N, rpb);
}

// Round 21
// 93.368 us; speedup vs baseline: 1.3171x; 1.3171x over previous
//
#include <hip/hip_runtime.h>

typedef float f32x4 __attribute__((ext_vector_type(4)));

// R21 = R19 (86.1us baseline) with ONE change: K1 PBY 32 -> 64 (512 blocks,
// 2 waves/SIMD instead of 1). Final untested point on K1's block-count curve
// (256: 42us K1; 1024: +22us; 512: never sampled). If null -> roofline.
//
// x: [1, 2049, 8192] f32 ; lambda: [1, 8192] f32
// out: [1, 1+2048+8192, 8192] f32
//   row 0           : center = lam*x0 - 0.5*lam*lower
//   rows 1..2048    : x[e]*lam
//   rows 2049..10240: one value per crossing column at row cumsum(has)-1, else 0

// K1: fused errs-scale + per-row-chunk abs partial sums.
// col-sliced, NT loads + NT stores (proven best flags for mixed stream).
__global__ __launch_bounds__(256) void k_errs_partial(
    const float* __restrict__ x, const float* __restrict__ lam,
    float* __restrict__ out, float* __restrict__ partials,
    int N, int rowsPerChunk)
{
    const int col = (blockIdx.x * 256 + threadIdx.x) * 4;
    const int r0  = 1 + blockIdx.y * rowsPerChunk;
    const f32x4 l4 = *(const f32x4*)(lam + col);
    f32x4 acc = {0.f, 0.f, 0.f, 0.f};
    #pragma unroll 4
    for (int r = r0; r < r0 + rowsPerChunk; ++r) {
        const f32x4 v = __builtin_nontemporal_load((const f32x4*)(x + (size_t)r * N + col));
        acc.x += fabsf(v.x); acc.y += fabsf(v.y); acc.z += fabsf(v.z); acc.w += fabsf(v.w);
        __builtin_nontemporal_store(v * l4, (f32x4*)(out + (size_t)r * N + col));
    }
    *(f32x4*)(partials + (size_t)blockIdx.y * N + col) = acc;
}

// K2: reduce partials per column, write center (out row 0), flags, vals.
__global__ __launch_bounds__(256) void k_stats(
    const float* __restrict__ x, const float* __restrict__ lam,
    const float* __restrict__ partials,
    float* __restrict__ out, float* __restrict__ vals, int* __restrict__ flags,
    int N, int P)
{
    const int n = blockIdx.x * 256 + threadIdx.x;
    float s = 0.f;
    for (int p = 0; p < P; ++p) s += partials[(size_t)p * N + n];
    const float x0 = x[n];          // row 0 of x
    const float l  = lam[n];
    const float lower = x0 - s;
    const float upper = x0 + s;
    out[n] = l * x0 - l * lower * 0.5f;          // center
    const bool has = (lower < 0.f) && (upper > 0.f);
    flags[n] = has ? 1 : 0;
    vals[n]  = has ? (-l * lower * 0.5f) : 0.f;
}

// K3: single-block scan of flags -> inverse map colOfRow[r] = column (or -1).
__global__ __launch_bounds__(256) void k_scan(
    const int* __restrict__ flags, int* __restrict__ colOfRow, int N)
{
    __shared__ int waveSums[4];
    const int t    = threadIdx.x;
    const int per  = N / 256;         // 32
    const int base = t * per;
    int f[32];
    int cnt = 0;
    #pragma unroll
    for (int i = 0; i < 32; ++i) {
        f[i] = flags[base + i];
        cnt += f[i];
        colOfRow[base + i] = -1;      // init; ordered vs scatter by barrier below
    }
    const int lane = t & 63;
    const int wid  = t >> 6;
    int v = cnt;
    #pragma unroll
    for (int off = 1; off < 64; off <<= 1) {
        const int u = __shfl_up(v, off, 64);
        if (lane >= off) v += u;
    }
    if (lane == 63) waveSums[wid] = v;
    __syncthreads();
    int wadd = 0;
    for (int w = 0; w < wid; ++w) wadd += waveSums[w];
    int run = v - cnt + wadd;         // exclusive prefix
    #pragma unroll
    for (int i = 0; i < 32; ++i) {
        if (f[i]) { colOfRow[run] = base + i; run += 1; }
    }
}

// K4: extra block, row-owned: block b fills rpb=8 contiguous rows (256 KB
// linear) injecting vals[colOfRow[r]]. Plain stores (at 6.8 TB/s ceiling).
__global__ __launch_bounds__(256) void k_extra_rows(
    const float* __restrict__ vals, const int* __restrict__ colOfRow,
    float* __restrict__ outExtra, int N, int rowsPerBlock)
{
    const int t  = threadIdx.x;
    const int r0 = blockIdx.x * rowsPerBlock;
    for (int r = r0; r < r0 + rowsPerBlock; ++r) {
        const int   c  = colOfRow[r];             // broadcast scalar read
        const float vv = (c >= 0) ? vals[c] : 0.f;
        float* rowp = outExtra + (size_t)r * N;
        #pragma unroll
        for (int s = 0; s < 8; ++s) {
            const int col = (s * 256 + t) * 4;
            f32x4 o;
            o.x = (c == col    ) ? vv : 0.f;
            o.y = (c == col + 1) ? vv : 0.f;
            o.z = (c == col + 2) ? vv : 0.f;
            o.w = (c == col + 3) ? vv : 0.f;
            *(f32x4*)(rowp + col) = o;            // plain store
        }
    }
}

extern "C" void kernel_launch(void* const* d_in, const int* in_sizes, int n_in,
                              void* d_out, int out_size, void* d_ws, size_t ws_size,
                              hipStream_t stream) {
    const float* x   = (const float*)d_in[0];
    const float* lam = (const float*)d_in[1];
    float* out = (float*)d_out;

    const int N  = in_sizes[1];            // 8192
    const int E1 = in_sizes[0] / N;        // 2049
    const int E  = E1 - 1;                 // 2048

    // PBY=64: 512 blocks = 2 waves/SIMD (midpoint never sampled).
    int PBY = 32;
    for (int cand : {64, 32}) {
        const size_t need = ((size_t)cand * N + 3 * (size_t)N) * 4;
        if ((E % cand) == 0 && need <= ws_size) { PBY = cand; break; }
    }

    float* outExtra = out + (size_t)E1 * N;
    float* partials = (float*)d_ws;                     // [PBY][N]
    float* vals     = partials + (size_t)PBY * N;       // [N]
    int*   flags    = (int*)(vals + N);                 // [N]
    int*   colOfRow = flags + N;                        // [N]

    dim3 blk(256);

    dim3 g1(N / 1024, PBY);
    hipLaunchKernelGGL(k_errs_partial, g1, blk, 0, stream,
                       x, lam, out, partials, N, E / PBY);

    hipLaunchKernelGGL(k_stats, dim3(N / 256), blk, 0, stream,
                       x, lam, partials, out, vals, flags, N, PBY);

    hipLaunchKernelGGL(k_scan, dim3(1), blk, 0, stream,
                       flags, colOfRow, N);

    const int rpb = 8;                     // 1024 blocks, 256 KB linear per block
    hipLaunchKernelGGL(k_extra_rows, dim3(N / rpb), blk, 0, stream,
                       vals, colOfRow, outExtra, N, rpb);
}

// Round 22
// 86.366 us; speedup vs baseline: 1.4239x; 1.0811x over previous
//
#include <hip/hip_runtime.h>

typedef float f32x4 __attribute__((ext_vector_type(4)));

// FINAL (R12/R19 configuration — best measured: 86.1us, absmax 0).
// x: [1, 2049, 8192] f32 ; lambda: [1, 8192] f32
// out: [1, 1+2048+8192, 8192] f32
//   row 0           : center = lam*x0 - 0.5*lam*lower
//   rows 1..2048    : x[e]*lam
//   rows 2049..10240: one value per crossing column at row cumsum(has)-1, else 0
//
// Session-measured rules (gfx950):
//   - fused mixed r/w col-sliced stream: NT load + NT store, 256 blocks.
//     plain-store +12.6us (R13), plain-load +15.7us (R15), 512 blocks +7.3us
//     (R21), 1024 blocks +22us (R7), row-owned +57us (R14), linear +67us
//     (R18), pure-stream splits +20..37us (R16/R17/R20), ILP batch null (R10).
//   - linear store stream (K4): plain stores; NT costs ~20% (R5 vs R12).
//   - K4 row-owned 8 rows/block (256KB linear/block) = 6.8 TB/s = fill ceiling.
//     grid-stride fill +13us (R8), rpb=32 +4us (R11), VALU-thinning null (R9).

// K1: fused errs-scale + per-row-chunk abs partial sums.
__global__ __launch_bounds__(256) void k_errs_partial(
    const float* __restrict__ x, const float* __restrict__ lam,
    float* __restrict__ out, float* __restrict__ partials,
    int N, int rowsPerChunk)
{
    const int col = (blockIdx.x * 256 + threadIdx.x) * 4;
    const int r0  = 1 + blockIdx.y * rowsPerChunk;
    const f32x4 l4 = *(const f32x4*)(lam + col);
    f32x4 acc = {0.f, 0.f, 0.f, 0.f};
    #pragma unroll 4
    for (int r = r0; r < r0 + rowsPerChunk; ++r) {
        const f32x4 v = __builtin_nontemporal_load((const f32x4*)(x + (size_t)r * N + col));
        acc.x += fabsf(v.x); acc.y += fabsf(v.y); acc.z += fabsf(v.z); acc.w += fabsf(v.w);
        __builtin_nontemporal_store(v * l4, (f32x4*)(out + (size_t)r * N + col));
    }
    *(f32x4*)(partials + (size_t)blockIdx.y * N + col) = acc;
}

// K2: reduce partials per column, write center (out row 0), flags, vals.
__global__ __launch_bounds__(256) void k_stats(
    const float* __restrict__ x, const float* __restrict__ lam,
    const float* __restrict__ partials,
    float* __restrict__ out, float* __restrict__ vals, int* __restrict__ flags,
    int N, int P)
{
    const int n = blockIdx.x * 256 + threadIdx.x;
    float s = 0.f;
    for (int p = 0; p < P; ++p) s += partials[(size_t)p * N + n];
    const float x0 = x[n];          // row 0 of x
    const float l  = lam[n];
    const float lower = x0 - s;
    const float upper = x0 + s;
    out[n] = l * x0 - l * lower * 0.5f;          // center
    const bool has = (lower < 0.f) && (upper > 0.f);
    flags[n] = has ? 1 : 0;
    vals[n]  = has ? (-l * lower * 0.5f) : 0.f;
}

// K3: single-block scan of flags -> inverse map colOfRow[r] = column (or -1).
__global__ __launch_bounds__(256) void k_scan(
    const int* __restrict__ flags, int* __restrict__ colOfRow, int N)
{
    __shared__ int waveSums[4];
    const int t    = threadIdx.x;
    const int per  = N / 256;         // 32
    const int base = t * per;
    int f[32];
    int cnt = 0;
    #pragma unroll
    for (int i = 0; i < 32; ++i) {
        f[i] = flags[base + i];
        cnt += f[i];
        colOfRow[base + i] = -1;      // init; ordered vs scatter by barrier below
    }
    const int lane = t & 63;
    const int wid  = t >> 6;
    int v = cnt;
    #pragma unroll
    for (int off = 1; off < 64; off <<= 1) {
        const int u = __shfl_up(v, off, 64);
        if (lane >= off) v += u;
    }
    if (lane == 63) waveSums[wid] = v;
    __syncthreads();
    int wadd = 0;
    for (int w = 0; w < wid; ++w) wadd += waveSums[w];
    int run = v - cnt + wadd;         // exclusive prefix
    #pragma unroll
    for (int i = 0; i < 32; ++i) {
        if (f[i]) { colOfRow[run] = base + i; run += 1; }
    }
}

// K4: extra block, row-owned: block b fills 8 contiguous rows (256 KB linear)
// injecting vals[colOfRow[r]]. Plain stores.
__global__ __launch_bounds__(256) void k_extra_rows(
    const float* __restrict__ vals, const int* __restrict__ colOfRow,
    float* __restrict__ outExtra, int N, int rowsPerBlock)
{
    const int t  = threadIdx.x;
    const int r0 = blockIdx.x * rowsPerBlock;
    for (int r = r0; r < r0 + rowsPerBlock; ++r) {
        const int   c  = colOfRow[r];             // broadcast scalar read
        const float vv = (c >= 0) ? vals[c] : 0.f;
        float* rowp = outExtra + (size_t)r * N;
        #pragma unroll
        for (int s = 0; s < 8; ++s) {
            const int col = (s * 256 + t) * 4;
            f32x4 o;
            o.x = (c == col    ) ? vv : 0.f;
            o.y = (c == col + 1) ? vv : 0.f;
            o.z = (c == col + 2) ? vv : 0.f;
            o.w = (c == col + 3) ? vv : 0.f;
            *(f32x4*)(rowp + col) = o;            // plain store
        }
    }
}

extern "C" void kernel_launch(void* const* d_in, const int* in_sizes, int n_in,
                              void* d_out, int out_size, void* d_ws, size_t ws_size,
                              hipStream_t stream) {
    const float* x   = (const float*)d_in[0];
    const float* lam = (const float*)d_in[1];
    float* out = (float*)d_out;

    const int N  = in_sizes[1];            // 8192
    const int E1 = in_sizes[0] / N;        // 2049
    const int E  = E1 - 1;                 // 2048

    const int PBY = 32;
    float* outExtra = out + (size_t)E1 * N;

    float* partials = (float*)d_ws;                     // [PBY][N]
    float* vals     = partials + (size_t)PBY * N;       // [N]
    int*   flags    = (int*)(vals + N);                 // [N]
    int*   colOfRow = flags + N;                        // [N]

    dim3 blk(256);

    dim3 g1(N / 1024, PBY);
    hipLaunchKernelGGL(k_errs_partial, g1, blk, 0, stream,
                       x, lam, out, partials, N, E / PBY);

    hipLaunchKernelGGL(k_stats, dim3(N / 256), blk, 0, stream,
                       x, lam, partials, out, vals, flags, N, PBY);

    hipLaunchKernelGGL(k_scan, dim3(1), blk, 0, stream,
                       flags, colOfRow, N);

    const int rpb = 8;                     // 1024 blocks, 256 KB linear per block
    hipLaunchKernelGGL(k_extra_rows, dim3(N / rpb), blk, 0, stream,
                       vals, colOfRow, outExtra, N, rpb);
}